// Round 9
// baseline (451.333 us; speedup 1.0000x reference)
//
#include <hip/hip_runtime.h>
#include <hip/hip_bf16.h>
#include <stdint.h>

// ---------------- problem constants ----------------
#define EDGES   300000
#define NLIT    50000
#define NGRAPH  4
#define EPG     75000          // edges per graph (contiguous)
#define HDIM    64

// ws layout (bytes)
#define OFF_HL2C   0
#define OFF_HC2L   38400000
#define OFF_AGG    76800000
#define OFF_WT     89600000
#define OFF_ROACC  89681920
#define OFF_CNT    89682944
#define OFF_CSROFF 89882944
#define OFF_CURSOR 90082948
#define OFF_EIDX   90282948
#define OFF_BSUM   91482948
#define OFF_BBASE  91484000
#define OFF_M      91500032   // bf16 m fragments, 38.4 MB (new path only)
#define WS_NEED_M  (OFF_M + 38400000ULL)

// wT global layout: 10 "units", each [64 rows=out][64 cols=in] bf16 (4096 elems),
// stored LINEAR (unswizzled): elem (u,row,col) at u*4096 + row*64 + col.
// u0-2: msglT ; u3: merge0T cols 0-63 (m part) ; u4: merge0T cols 64-127 (h part)
// u5-6: mergeRT ; u7-9: msgcT
#define WT_TOTAL    40960
#define WT_CLS_ELEM 28672

#define LIT_WBYTES (7 * 8192)   // fused-fallback LDS staging
#define EPB2       256          // fused fallback: edges per block (8 waves x 32)
#define GRID_FUSED ((EDGES + EPB2 - 1) / EPB2)

#define NWCH       (EDGES / 32)     // 9375 wave-chunks, exact
#define REG_GRID   512              // 512 blocks x 4 waves = 2048 waves
#define REG_WAVES  (REG_GRID * 4)

#define SCAN_BLOCKS ((NLIT + 255) / 256)   // 196

typedef __attribute__((ext_vector_type(8)))  short          s16x8;
typedef __attribute__((ext_vector_type(8)))  unsigned short u16x8;
typedef __attribute__((ext_vector_type(4)))  unsigned short u16x4;
typedef __attribute__((ext_vector_type(4)))  float          f32x4;
typedef __attribute__((ext_vector_type(16))) float          f32x16;

__device__ __forceinline__ f32x16 mfma32(s16x8 a, s16x8 b, f32x16 c) {
    return __builtin_amdgcn_mfma_f32_32x32x16_bf16(a, b, c, 0, 0, 0);
}
__device__ __forceinline__ float bf2f(unsigned short s) {
    union { unsigned int u; float f; } v; v.u = ((unsigned int)s) << 16; return v.f;
}
__device__ __forceinline__ unsigned short f2bf(float f) {
    union { __hip_bfloat16 b; unsigned short s; } v;
    v.b = __float2bfloat16(f);
    return v.s;
}
__device__ __forceinline__ unsigned pk2(float a, float b) {
    return (unsigned)f2bf(a) | ((unsigned)f2bf(b) << 16);
}

// ---- register-weight layer: weights wA[kb*2+t] held in VGPRs, bias from global ----
__device__ __forceinline__ void layer32r(const s16x8 (&wA)[8],
                                         const float* __restrict__ biasG,
                                         const s16x8 (&bin)[4], f32x16 (&acc)[2],
                                         int hi)
{
#pragma unroll
    for (int t = 0; t < 2; ++t)
#pragma unroll
        for (int g = 0; g < 4; ++g) {
            f32x4 bv = *(const f32x4*)(biasG + 32 * t + 8 * g + 4 * hi);
#pragma unroll
            for (int r = 0; r < 4; ++r) acc[t][4 * g + r] = bv[r];
        }
    __builtin_amdgcn_s_setprio(1);
#pragma unroll
    for (int kb = 0; kb < 4; ++kb)
#pragma unroll
        for (int t = 0; t < 2; ++t)
            acc[t] = mfma32(wA[kb * 2 + t], bin[kb], acc[t]);
    __builtin_amdgcn_s_setprio(0);
}

__device__ __forceinline__ void load_wunit(const unsigned short* __restrict__ wu,
                                           int eL, int hi, s16x8 (&wA)[8])
{
#pragma unroll
    for (int kb = 0; kb < 4; ++kb)
#pragma unroll
        for (int t = 0; t < 2; ++t)
            wA[kb * 2 + t] = *(const s16x8*)(wu + (32 * t + eL) * 64 + 32 * kb + 16 * hi);
}

// in-register C->B relayout: per kb, slots come from own regs + lane^32 partner
template<bool RELU>
__device__ __forceinline__ void relayout32(f32x16 (&acc)[2], s16x8 (&bout)[4],
                                           int bpidx, int hi)
{
    if (RELU) {
#pragma unroll
        for (int t = 0; t < 2; ++t)
#pragma unroll
            for (int i = 0; i < 16; ++i) acc[t][i] = fmaxf(acc[t][i], 0.f);
    }
#pragma unroll
    for (int kb = 0; kb < 4; ++kb) {
        int m0 = 2 * kb, m1 = 2 * kb + 1;
        int t0 = m0 >> 2, g0 = m0 & 3, t1 = m1 >> 2, g1 = m1 & 3;
        unsigned A0 = pk2(acc[t0][4 * g0 + 0], acc[t0][4 * g0 + 1]);
        unsigned A1 = pk2(acc[t0][4 * g0 + 2], acc[t0][4 * g0 + 3]);
        unsigned B0 = pk2(acc[t1][4 * g1 + 0], acc[t1][4 * g1 + 1]);
        unsigned B1 = pk2(acc[t1][4 * g1 + 2], acc[t1][4 * g1 + 3]);
        unsigned pA0 = (unsigned)__builtin_amdgcn_ds_bpermute(bpidx, (int)A0);
        unsigned pA1 = (unsigned)__builtin_amdgcn_ds_bpermute(bpidx, (int)A1);
        unsigned pB0 = (unsigned)__builtin_amdgcn_ds_bpermute(bpidx, (int)B0);
        unsigned pB1 = (unsigned)__builtin_amdgcn_ds_bpermute(bpidx, (int)B1);
        union { unsigned w[4]; s16x8 v; } u;
        u.w[0] = hi ? pB0 : A0;
        u.w[1] = hi ? pB1 : A1;
        u.w[2] = hi ? B0 : pA0;
        u.w[3] = hi ? B1 : pA1;
        bout[kb] = u.v;
    }
}

__device__ __forceinline__ void store32(const f32x16 (&acc)[2],
                                        unsigned short* __restrict__ dst, int hi)
{
#pragma unroll
    for (int t = 0; t < 2; ++t)
#pragma unroll
        for (int g = 0; g < 4; ++g) {
            u16x4 p;
#pragma unroll
            for (int r = 0; r < 4; ++r) p[r] = f2bf(acc[t][4 * g + r]);
            *(u16x4*)(dst + 32 * t + 8 * g + 4 * hi) = p;
        }
}

// -------- transpose + bf16 all round weights into LINEAR unit layout --------
__global__ __launch_bounds__(256) void prep_weights(
    const float* __restrict__ msgl_W, const float* __restrict__ merge_W0,
    const float* __restrict__ merge_Wr, const float* __restrict__ msgc_W,
    unsigned short* __restrict__ wT)
{
    int gid = blockIdx.x * 256 + threadIdx.x;
    if (gid >= WT_TOTAL) return;
    int unit = gid >> 12;
    int o = (gid >> 6) & 63;              // row = out
    int i = gid & 63;                     // col = in
    float v;
    if (unit < 3)       v = msgl_W[unit * 4096 + i * 64 + o];
    else if (unit < 5)  v = merge_W0[((unit - 3) * 64 + i) * 64 + o];
    else if (unit < 7)  v = merge_Wr[(unit - 5) * 4096 + i * 64 + o];
    else                v = msgc_W[(unit - 7) * 4096 + i * 64 + o];
    wT[gid] = f2bf(v);
}

// -------- CSR build --------
__global__ __launch_bounds__(256) void csr_hist(const int* __restrict__ lit_idx,
                                                int* __restrict__ cnt)
{
    int e = blockIdx.x * 256 + threadIdx.x;
    if (e < EDGES) atomicAdd(&cnt[lit_idx[e]], 1);
}

__global__ __launch_bounds__(256) void scan1(const int* __restrict__ cnt,
                                             int* __restrict__ bsum)
{
    __shared__ int red[4];
    int i = blockIdx.x * 256 + threadIdx.x;
    int s = (i < NLIT) ? cnt[i] : 0;
#pragma unroll
    for (int off = 1; off < 64; off <<= 1) s += __shfl_xor(s, off, 64);
    if ((threadIdx.x & 63) == 0) red[threadIdx.x >> 6] = s;
    __syncthreads();
    if (threadIdx.x == 0) bsum[blockIdx.x] = red[0] + red[1] + red[2] + red[3];
}

__global__ __launch_bounds__(256) void scan2(const int* __restrict__ bsum,
                                             int* __restrict__ bbase)
{
    __shared__ int tmp[256];
    int t = threadIdx.x;
    int v = (t < SCAN_BLOCKS) ? bsum[t] : 0;
    tmp[t] = v;
    __syncthreads();
#pragma unroll
    for (int off = 1; off < 256; off <<= 1) {
        int add = (t >= off) ? tmp[t - off] : 0;
        __syncthreads();
        tmp[t] += add;
        __syncthreads();
    }
    if (t < SCAN_BLOCKS) bbase[t] = tmp[t] - v;   // exclusive
}

__global__ __launch_bounds__(256) void scan3(const int* __restrict__ cnt,
                                             const int* __restrict__ bbase,
                                             int* __restrict__ off,
                                             int* __restrict__ cursor)
{
    __shared__ int tmp[256];
    int t = threadIdx.x;
    int i = blockIdx.x * 256 + t;
    int v = (i < NLIT) ? cnt[i] : 0;
    tmp[t] = v;
    __syncthreads();
#pragma unroll
    for (int offs = 1; offs < 256; offs <<= 1) {
        int add = (t >= offs) ? tmp[t - offs] : 0;
        __syncthreads();
        tmp[t] += add;
        __syncthreads();
    }
    if (i < NLIT) {
        int ex = bbase[blockIdx.x] + tmp[t] - v;
        off[i] = ex; cursor[i] = ex;
    }
    if (i == NLIT - 1) off[NLIT] = EDGES;
}

__global__ __launch_bounds__(256) void csr_scatter(const int* __restrict__ lit_idx,
                                                   int* __restrict__ cursor,
                                                   int* __restrict__ eidx)
{
    int e = blockIdx.x * 256 + threadIdx.x;
    if (e >= EDGES) return;
    int pos = atomicAdd(&cursor[lit_idx[e]], 1);
    eidx[pos] = e;
}

// -------- gather aggregation, group-of-4 latency breaking --------
__global__ __launch_bounds__(256) void aggregate(const unsigned short* __restrict__ h_c2l,
                                                 const int* __restrict__ off,
                                                 const int* __restrict__ eidx,
                                                 float* __restrict__ agg)
{
    int t = threadIdx.x;
    int lane8 = t & 7;
    int lit = blockIdx.x * 32 + (t >> 3);
    if (lit >= NLIT) return;
    int lo = off[lit], hi = off[lit + 1];
    float s[8] = {0, 0, 0, 0, 0, 0, 0, 0};
    int i = lo;
    for (; i + 4 <= hi; i += 4) {
        int e0 = eidx[i], e1 = eidx[i + 1], e2 = eidx[i + 2], e3 = eidx[i + 3];
        u16x8 v0 = *(const u16x8*)(h_c2l + e0 * 64 + lane8 * 8);
        u16x8 v1 = *(const u16x8*)(h_c2l + e1 * 64 + lane8 * 8);
        u16x8 v2 = *(const u16x8*)(h_c2l + e2 * 64 + lane8 * 8);
        u16x8 v3 = *(const u16x8*)(h_c2l + e3 * 64 + lane8 * 8);
#pragma unroll
        for (int j = 0; j < 8; ++j)
            s[j] += (bf2f(v0[j]) + bf2f(v1[j])) + (bf2f(v2[j]) + bf2f(v3[j]));
    }
    for (; i < hi; ++i) {
        int e = eidx[i];
        u16x8 hv = *(const u16x8*)(h_c2l + e * 64 + lane8 * 8);
#pragma unroll
        for (int j = 0; j < 8; ++j) s[j] += bf2f(hv[j]);
    }
    f32x4 a0, a1;
    a0[0] = s[0]; a0[1] = s[1]; a0[2] = s[2]; a0[3] = s[3];
    a1[0] = s[4]; a1[1] = s[5]; a1[2] = s[6]; a1[3] = s[7];
    *(f32x4*)(agg + lit * 64 + lane8 * 8)     = a0;
    *(f32x4*)(agg + lit * 64 + lane8 * 8 + 4) = a1;
}

// -------- init --------
__global__ __launch_bounds__(256) void init_kernel(
    const float* __restrict__ feat_l2c, const float* __restrict__ feat_c2l,
    const float* __restrict__ W_l2c, const float* __restrict__ b_l2c,
    const float* __restrict__ W_c2l, const float* __restrict__ b_c2l,
    unsigned short* __restrict__ h_l2c, unsigned short* __restrict__ h_c2l)
{
    int gid = blockIdx.x * 256 + threadIdx.x;
    if (gid >= EDGES * 8) return;
    int e = gid >> 3, fo = (gid & 7) << 3;
    float2 fl = *(const float2*)(feat_l2c + e * 2);
    float2 fc = *(const float2*)(feat_c2l + e * 2);

    u16x8 outl, outc;
#pragma unroll
    for (int j = 0; j < 8; ++j) {
        float wl0 = W_l2c[fo + j], wl1 = W_l2c[64 + fo + j];
        float wc0 = W_c2l[fo + j], wc1 = W_c2l[64 + fo + j];
        float vl = fl.x * wl0 + fl.y * wl1 + b_l2c[fo + j];
        float vc = fc.x * wc0 + fc.y * wc1 + b_c2l[fo + j];
        outl[j] = f2bf(vl);
        outc[j] = f2bf(vc);
    }
    *(u16x8*)(h_l2c + e * 64 + fo) = outl;
    *(u16x8*)(h_c2l + e * 64 + fo) = outc;
}

// -------- NEW: lit_msg — msgl 3-layer MLP, weights in registers, m -> ws --------
__global__ __launch_bounds__(256, 2) void lit_msg(
    const unsigned short* __restrict__ h_c2l,
    const float* __restrict__ agg,
    const int* __restrict__ lit_idx,
    const unsigned short* __restrict__ wT,
    const float* __restrict__ msgl_b,
    unsigned short* __restrict__ m_ws)
{
    int tid = threadIdx.x;
    int wv = tid >> 6, lane = tid & 63;
    int eL = lane & 31, hi = lane >> 5;
    int bpidx = (lane ^ 32) << 2;

    s16x8 w0[8], w1[8], w2[8];
    load_wunit(wT,            eL, hi, w0);
    load_wunit(wT + 4096,     eL, hi, w1);
    load_wunit(wT + 2 * 4096, eL, hi, w2);

    int wid = blockIdx.x * 4 + wv;
    for (int w = wid; w < NWCH; w += REG_WAVES) {
        int e = w * 32 + eL;
        int lit = lit_idx[e];

        s16x8 binp[4];
#pragma unroll
        for (int k = 0; k < 4; ++k) {
            int f0 = 16 * k + 8 * hi;
            f32x4 a0 = *(const f32x4*)(agg + lit * 64 + f0);
            f32x4 a1 = *(const f32x4*)(agg + lit * 64 + f0 + 4);
            u16x8 hv = *(const u16x8*)(h_c2l + e * 64 + f0);
            s16x8 b;
#pragma unroll
            for (int j = 0; j < 4; ++j) b[j]     = (short)f2bf((a0[j] - bf2f(hv[j]))     * 0.125f);
#pragma unroll
            for (int j = 0; j < 4; ++j) b[4 + j] = (short)f2bf((a1[j] - bf2f(hv[4 + j])) * 0.125f);
            binp[k] = b;
        }

        f32x16 acc[2];
        s16x8 bf[4];
        layer32r(w0, msgl_b,       binp, acc, hi);
        relayout32<true >(acc, bf, bpidx, hi);
        layer32r(w1, msgl_b + 64,  bf, acc, hi);
        relayout32<true >(acc, bf, bpidx, hi);
        layer32r(w2, msgl_b + 128, bf, acc, hi);
        relayout32<false>(acc, bf, bpidx, hi);

        // store m fragments: kb-major, lane-contiguous (fully coalesced 1KB/wave per kb)
        unsigned short* mb = m_ws + w * 2048;
#pragma unroll
        for (int kb = 0; kb < 4; ++kb)
            *(u16x8*)(mb + kb * 512 + lane * 8) = *(const u16x8*)&bf[kb];
    }
}

// -------- NEW: lit_merge — merge0(K=128)+mergeR x2, weights in registers --------
__global__ __launch_bounds__(256, 2) void lit_merge(
    unsigned short* __restrict__ h_l2c,
    const unsigned short* __restrict__ m_ws,
    const unsigned short* __restrict__ wT,
    const float* __restrict__ merge_b0,
    const float* __restrict__ merge_br)
{
    int tid = threadIdx.x;
    int wv = tid >> 6, lane = tid & 63;
    int eL = lane & 31, hi = lane >> 5;
    int bpidx = (lane ^ 32) << 2;

    s16x8 wm[8], wh[8], wr0[8], wr1[8];
    load_wunit(wT + 3 * 4096, eL, hi, wm);   // merge0 m-part
    load_wunit(wT + 4 * 4096, eL, hi, wh);   // merge0 h-part
    load_wunit(wT + 5 * 4096, eL, hi, wr0);
    load_wunit(wT + 6 * 4096, eL, hi, wr1);

    int wid = blockIdx.x * 4 + wv;
    for (int w = wid; w < NWCH; w += REG_WAVES) {
        int e = w * 32 + eL;

        s16x8 mf[4], hfrag[4];
        const unsigned short* mb = m_ws + w * 2048;
#pragma unroll
        for (int kb = 0; kb < 4; ++kb)
            mf[kb] = *(const s16x8*)(mb + kb * 512 + lane * 8);
#pragma unroll
        for (int k = 0; k < 4; ++k)
            hfrag[k] = *(const s16x8*)(h_l2c + e * 64 + 16 * k + 8 * hi);

        f32x16 acc[2];
#pragma unroll
        for (int t = 0; t < 2; ++t)
#pragma unroll
            for (int g = 0; g < 4; ++g) {
                f32x4 bv = *(const f32x4*)(merge_b0 + 32 * t + 8 * g + 4 * hi);
#pragma unroll
                for (int r = 0; r < 4; ++r) acc[t][4 * g + r] = bv[r];
            }
        __builtin_amdgcn_s_setprio(1);
#pragma unroll
        for (int kb = 0; kb < 4; ++kb)
#pragma unroll
            for (int t = 0; t < 2; ++t)
                acc[t] = mfma32(wm[kb * 2 + t], mf[kb], acc[t]);
#pragma unroll
        for (int kb = 0; kb < 4; ++kb)
#pragma unroll
            for (int t = 0; t < 2; ++t)
                acc[t] = mfma32(wh[kb * 2 + t], hfrag[kb], acc[t]);
        __builtin_amdgcn_s_setprio(0);

        s16x8 bf[4];
        relayout32<true>(acc, bf, bpidx, hi);
        layer32r(wr0, merge_br,      bf, acc, hi);
        relayout32<true>(acc, bf, bpidx, hi);
        layer32r(wr1, merge_br + 64, bf, acc, hi);

        store32(acc, h_l2c + e * 64, hi);
    }
}

// -------- NEW: clause update, weights in registers --------
__global__ __launch_bounds__(256, 2) void clause_reg(
    const unsigned short* __restrict__ h_l2c,
    unsigned short* __restrict__ h_c2l,
    const unsigned short* __restrict__ wT,
    const float* __restrict__ msgc_b)
{
    int tid = threadIdx.x;
    int wv = tid >> 6, lane = tid & 63;
    int eL = lane & 31, hi = lane >> 5;
    int bpidx = (lane ^ 32) << 2;

    s16x8 w0[8], w1[8], w2[8];
    load_wunit(wT + WT_CLS_ELEM,            eL, hi, w0);
    load_wunit(wT + WT_CLS_ELEM + 4096,     eL, hi, w1);
    load_wunit(wT + WT_CLS_ELEM + 2 * 4096, eL, hi, w2);

    int wid = blockIdx.x * 4 + wv;
    for (int w = wid; w < NWCH; w += REG_WAVES) {
        int e = w * 32 + eL;
        int c3 = (e / 3) * 3;
        int d = e - c3;
        int e1 = c3 + (d == 0 ? 1 : 0);
        int e2 = c3 + (d == 2 ? 1 : 2);

        s16x8 binp[4];
#pragma unroll
        for (int k = 0; k < 4; ++k) {
            int f0 = 16 * k + 8 * hi;
            u16x8 h1 = *(const u16x8*)(h_l2c + e1 * 64 + f0);
            u16x8 h2 = *(const u16x8*)(h_l2c + e2 * 64 + f0);
            s16x8 b;
#pragma unroll
            for (int j = 0; j < 8; ++j)
                b[j] = (short)f2bf((bf2f(h1[j]) + bf2f(h2[j])) * 0.125f);
            binp[k] = b;
        }

        f32x16 acc[2];
        s16x8 bf[4];
        layer32r(w0, msgc_b,       binp, acc, hi);
        relayout32<true>(acc, bf, bpidx, hi);
        layer32r(w1, msgc_b + 64,  bf, acc, hi);
        relayout32<true>(acc, bf, bpidx, hi);
        layer32r(w2, msgc_b + 128, bf, acc, hi);

        store32(acc, h_c2l + e * 64, hi);
    }
}

// -------- FALLBACK: fused lit_update (R5 structure, stage-time swizzle) --------
__global__ __launch_bounds__(512, 4) void lit_fused(
    const unsigned short* __restrict__ h_c2l,
    unsigned short* __restrict__ h_l2c,
    const float* __restrict__ agg,
    const int* __restrict__ lit_idx,
    const unsigned short* __restrict__ wT,
    const float* __restrict__ msgl_b,
    const float* __restrict__ merge_b0,
    const float* __restrict__ merge_br)
{
    __shared__ __align__(16) char lds[LIT_WBYTES + 384 * 4];
    int tid = threadIdx.x;
    for (int c = tid; c < LIT_WBYTES / 16; c += 512) {
        u16x8 v = *(const u16x8*)(wT + c * 8);
        int u = c >> 9, row = (c >> 3) & 63, slot = c & 7;
        *(u16x8*)(lds + u * 8192 + row * 128 + ((slot * 16) ^ ((row & 7) << 4))) = v;
    }
    float* ldsBias = (float*)(lds + LIT_WBYTES);
    if (tid < 384) {
        float v;
        if (tid < 192)      v = msgl_b[tid];
        else if (tid < 256) v = merge_b0[tid - 192];
        else                v = merge_br[tid - 256];
        ldsBias[tid] = v;
    }
    __syncthreads();

    int wv = tid >> 6, lane = tid & 63;
    int eL = lane & 31, hi = lane >> 5;
    int bpidx = (lane ^ 32) << 2;
    int base = blockIdx.x * EPB2 + wv * 32;
    if (base >= EDGES) return;
    int e = base + eL;
    int lit = lit_idx[e];

    s16x8 hfrag[4];
#pragma unroll
    for (int k = 0; k < 4; ++k)
        hfrag[k] = *(const s16x8*)(h_l2c + e * 64 + 16 * k + 8 * hi);

    s16x8 binp[4];
#pragma unroll
    for (int k = 0; k < 4; ++k) {
        int f0 = 16 * k + 8 * hi;
        f32x4 a0 = *(const f32x4*)(agg + lit * 64 + f0);
        f32x4 a1 = *(const f32x4*)(agg + lit * 64 + f0 + 4);
        u16x8 hv = *(const u16x8*)(h_c2l + e * 64 + f0);
        s16x8 b;
#pragma unroll
        for (int j = 0; j < 4; ++j) b[j]     = (short)f2bf((a0[j] - bf2f(hv[j]))     * 0.125f);
#pragma unroll
        for (int j = 0; j < 4; ++j) b[4 + j] = (short)f2bf((a1[j] - bf2f(hv[4 + j])) * 0.125f);
        binp[k] = b;
    }

    f32x16 acc[2];
    s16x8 bf[4];
    // LDS layer helper inlined (swizzled reads)
#define LDS_LAYER(UB, BIASOFF, BIN)                                                   \
    {                                                                                 \
        const char* ub = lds + (UB) * 8192;                                           \
        const float* bl = ldsBias + (BIASOFF);                                        \
        _Pragma("unroll")                                                             \
        for (int t = 0; t < 2; ++t)                                                   \
            _Pragma("unroll")                                                         \
            for (int g = 0; g < 4; ++g) {                                             \
                f32x4 bv = *(const f32x4*)(bl + 32 * t + 8 * g + 4 * hi);             \
                _Pragma("unroll")                                                     \
                for (int r = 0; r < 4; ++r) acc[t][4 * g + r] = bv[r];                \
            }                                                                         \
        _Pragma("unroll")                                                             \
        for (int kb = 0; kb < 4; ++kb)                                                \
            _Pragma("unroll")                                                         \
            for (int t = 0; t < 2; ++t) {                                             \
                int row = 32 * t + eL;                                                \
                s16x8 a = *(const s16x8*)(ub + row * 128 +                            \
                                          ((32 * kb + 16 * hi) ^ ((row & 7) << 4)));  \
                acc[t] = mfma32(a, (BIN)[kb], acc[t]);                                \
            }                                                                         \
    }

    LDS_LAYER(0, 0,   binp);
    relayout32<true >(acc, bf, bpidx, hi);
    LDS_LAYER(1, 64,  bf);
    relayout32<true >(acc, bf, bpidx, hi);
    LDS_LAYER(2, 128, bf);
    relayout32<false>(acc, bf, bpidx, hi);

#pragma unroll
    for (int t = 0; t < 2; ++t)
#pragma unroll
        for (int g = 0; g < 4; ++g) {
            f32x4 bv = *(const f32x4*)(ldsBias + 192 + 32 * t + 8 * g + 4 * hi);
#pragma unroll
            for (int r = 0; r < 4; ++r) acc[t][4 * g + r] = bv[r];
        }
#pragma unroll
    for (int kb = 0; kb < 8; ++kb) {
        const char* ub = lds + (3 + (kb >> 2)) * 8192;
        s16x8 bop = (kb < 4) ? bf[kb] : hfrag[kb - 4];
#pragma unroll
        for (int t = 0; t < 2; ++t) {
            int row = 32 * t + eL;
            s16x8 a = *(const s16x8*)(ub + row * 128 +
                                      ((32 * (kb & 3) + 16 * hi) ^ ((row & 7) << 4)));
            acc[t] = mfma32(a, bop, acc[t]);
        }
    }
    relayout32<true>(acc, bf, bpidx, hi);
    LDS_LAYER(5, 256, bf);
    relayout32<true>(acc, bf, bpidx, hi);
    LDS_LAYER(6, 320, bf);
#undef LDS_LAYER

    store32(acc, h_l2c + e * 64, hi);
}

// -------- readout --------
__global__ __launch_bounds__(256) void readout_sum(
    const unsigned short* __restrict__ h_c2l, float* __restrict__ ro_acc)
{
    __shared__ float lsum[32][64];
    int g = blockIdx.x >> 6, chunk = blockIdx.x & 63;
    int t = threadIdx.x;
    int fg = t & 7, el = t >> 3;
    float s[8] = {0, 0, 0, 0, 0, 0, 0, 0};
    for (int idx = chunk * 32 + el; idx < EPG; idx += 2048) {
        u16x8 hv = *(const u16x8*)(h_c2l + (g * EPG + idx) * 64 + fg * 8);
#pragma unroll
        for (int j = 0; j < 8; ++j) s[j] += bf2f(hv[j]);
    }
#pragma unroll
    for (int j = 0; j < 8; ++j) lsum[el][fg * 8 + j] = s[j];
    __syncthreads();
    if (t < 64) {
        float tot = 0.f;
#pragma unroll 8
        for (int r = 0; r < 32; ++r) tot += lsum[r][t];
        atomicAdd(&ro_acc[g * 64 + t], tot);
    }
}

__global__ __launch_bounds__(256) void readout_mlp(
    const float* __restrict__ ro_acc, const float* __restrict__ ro_W,
    const float* __restrict__ ro_b, const float* __restrict__ ro_W2,
    const float* __restrict__ ro_b2, float* __restrict__ out)
{
    __shared__ float xb[NGRAPH][HDIM];
    __shared__ float yb[NGRAPH][HDIM];
    int g = threadIdx.x >> 6;
    int j = threadIdx.x & 63;
    xb[g][j] = ro_acc[g * HDIM + j] * (1.0f / 12500.0f);
    __syncthreads();
    float a = ro_b[j];
#pragma unroll 8
    for (int k = 0; k < HDIM; ++k) a += xb[g][k] * ro_W[k * HDIM + j];
    a = fmaxf(a, 0.0f);
    yb[g][j] = a;
    __syncthreads();
    float a2 = ro_b[HDIM + j];
#pragma unroll 8
    for (int k = 0; k < HDIM; ++k) a2 += yb[g][k] * ro_W[4096 + k * HDIM + j];
    a2 = fmaxf(a2, 0.0f);
    float p = a2 * ro_W2[j];
#pragma unroll
    for (int off = 32; off > 0; off >>= 1) p += __shfl_down(p, off, 64);
    if (j == 0) out[g] = 1.0f / (1.0f + expf(-(p + ro_b2[0])));
}

extern "C" void kernel_launch(void* const* d_in, const int* in_sizes, int n_in,
                              void* d_out, int out_size, void* d_ws, size_t ws_size,
                              hipStream_t stream)
{
    const float* feat_l2c = (const float*)d_in[0];
    const float* feat_c2l = (const float*)d_in[1];
    const int*   lit_idx  = (const int*)d_in[2];
    const float* W_l2c    = (const float*)d_in[4];
    const float* b_l2c    = (const float*)d_in[5];
    const float* W_c2l    = (const float*)d_in[6];
    const float* b_c2l    = (const float*)d_in[7];
    const float* msgl_W   = (const float*)d_in[8];
    const float* msgl_b   = (const float*)d_in[9];
    const float* merge_W0 = (const float*)d_in[10];
    const float* merge_b0 = (const float*)d_in[11];
    const float* merge_Wr = (const float*)d_in[12];
    const float* merge_br = (const float*)d_in[13];
    const float* msgc_W   = (const float*)d_in[14];
    const float* msgc_b   = (const float*)d_in[15];
    const float* ro_W     = (const float*)d_in[16];
    const float* ro_b     = (const float*)d_in[17];
    const float* ro_W2    = (const float*)d_in[18];
    const float* ro_b2    = (const float*)d_in[19];

    char* ws = (char*)d_ws;
    unsigned short* h_l2c  = (unsigned short*)(ws + OFF_HL2C);
    unsigned short* h_c2l  = (unsigned short*)(ws + OFF_HC2L);
    float*          agg    = (float*)(ws + OFF_AGG);
    unsigned short* wT     = (unsigned short*)(ws + OFF_WT);
    float*          ro_acc = (float*)(ws + OFF_ROACC);
    int*            cnt    = (int*)(ws + OFF_CNT);
    int*            csroff = (int*)(ws + OFF_CSROFF);
    int*            cursor = (int*)(ws + OFF_CURSOR);
    int*            eidx   = (int*)(ws + OFF_EIDX);
    int*            bsum   = (int*)(ws + OFF_BSUM);
    int*            bbase  = (int*)(ws + OFF_BBASE);
    unsigned short* m_ws   = (unsigned short*)(ws + OFF_M);

    const bool use_split = (ws_size >= WS_NEED_M);   // deterministic per-launch

    hipMemsetAsync(cnt, 0, NLIT * sizeof(int), stream);
    hipMemsetAsync(ro_acc, 0, NGRAPH * 64 * sizeof(float), stream);

    prep_weights<<<(WT_TOTAL + 255) / 256, 256, 0, stream>>>(msgl_W, merge_W0, merge_Wr, msgc_W, wT);

    csr_hist<<<(EDGES + 255) / 256, 256, 0, stream>>>(lit_idx, cnt);
    scan1<<<SCAN_BLOCKS, 256, 0, stream>>>(cnt, bsum);
    scan2<<<1, 256, 0, stream>>>(bsum, bbase);
    scan3<<<SCAN_BLOCKS, 256, 0, stream>>>(cnt, bbase, csroff, cursor);
    csr_scatter<<<(EDGES + 255) / 256, 256, 0, stream>>>(lit_idx, cursor, eidx);

    init_kernel<<<EDGES * 8 / 256, 256, 0, stream>>>(feat_l2c, feat_c2l, W_l2c, b_l2c,
                                                     W_c2l, b_c2l, h_l2c, h_c2l);
    for (int r = 0; r < 3; ++r) {
        aggregate<<<(NLIT + 31) / 32, 256, 0, stream>>>(h_c2l, csroff, eidx, agg);
        if (use_split) {
            lit_msg<<<REG_GRID, 256, 0, stream>>>(h_c2l, agg, lit_idx, wT, msgl_b, m_ws);
            lit_merge<<<REG_GRID, 256, 0, stream>>>(h_l2c, m_ws, wT, merge_b0, merge_br);
        } else {
            lit_fused<<<GRID_FUSED, 512, 0, stream>>>(h_c2l, h_l2c, agg, lit_idx, wT,
                                                      msgl_b, merge_b0, merge_br);
        }
        clause_reg<<<REG_GRID, 256, 0, stream>>>(h_l2c, h_c2l, wT, msgc_b);
    }
    readout_sum<<<256, 256, 0, stream>>>(h_c2l, ro_acc);
    readout_mlp<<<1, 256, 0, stream>>>(ro_acc, ro_W, ro_b, ro_W2, ro_b2, (float*)d_out);
}

// Round 10
// 378.391 us; speedup vs baseline: 1.1928x; 1.1928x over previous
//
#include <hip/hip_runtime.h>
#include <hip/hip_bf16.h>
#include <stdint.h>

// ---------------- problem constants ----------------
#define EDGES   300000
#define NLIT    50000
#define NGRAPH  4
#define EPG     75000          // edges per graph (contiguous)
#define HDIM    64

// ws layout (bytes)
#define OFF_HL2C   0
#define OFF_HC2L   38400000
#define OFF_AGG    76800000
#define OFF_WT     89600000
#define OFF_ROACC  89681920
#define OFF_CNT    89682944
#define OFF_CSROFF 89882944
#define OFF_CURSOR 90082948
#define OFF_EIDX   90282948
#define OFF_BSUM   91482948
#define OFF_BBASE  91484000

// wT global layout: 10 "units", each [64 rows=out][64 cols=in] bf16 (4096 elems),
// stored PRE-SWIZZLED: element (u,row,col) at u*4096 + row*64 + (col ^ ((row&7)<<3)).
// u0-2: msglT ; u3: merge0T cols 0-63 (m part) ; u4: merge0T cols 64-127 (h part)
// u5-6: mergeRT ; u7-9: msgcT
#define WT_TOTAL    40960
#define WT_CLS_ELEM 28672      // element offset of clause units (u7)

#define LIT_WBYTES (7 * 8192)   // 57344
#define CLS_WBYTES (3 * 8192)   // 24576
#define LIT_EPB    512          // lit: 8 waves x 64 edges (2 chunks/wave)
#define LIT_GRID   ((EDGES + LIT_EPB - 1) / LIT_EPB)   // 586
#define CLS_EPB    256          // clause: 8 waves x 32 edges
#define CLS_GRID   ((EDGES + CLS_EPB - 1) / CLS_EPB)   // 1172

#define SCAN_BLOCKS ((NLIT + 255) / 256)   // 196

typedef __attribute__((ext_vector_type(8)))  short          s16x8;
typedef __attribute__((ext_vector_type(8)))  unsigned short u16x8;
typedef __attribute__((ext_vector_type(4)))  unsigned short u16x4;
typedef __attribute__((ext_vector_type(4)))  float          f32x4;
typedef __attribute__((ext_vector_type(16))) float          f32x16;

__device__ __forceinline__ f32x16 mfma32(s16x8 a, s16x8 b, f32x16 c) {
    return __builtin_amdgcn_mfma_f32_32x32x16_bf16(a, b, c, 0, 0, 0);
}
__device__ __forceinline__ float bf2f(unsigned short s) {
    union { unsigned int u; float f; } v; v.u = ((unsigned int)s) << 16; return v.f;
}
// native RNE convert (compiler emits v_cvt_pk_bf16_f32 for pairs)
__device__ __forceinline__ unsigned short f2bf(float f) {
    union { __hip_bfloat16 b; unsigned short s; } v;
    v.b = __float2bfloat16(f);
    return v.s;
}
__device__ __forceinline__ unsigned pk2(float a, float b) {
    return (unsigned)f2bf(a) | ((unsigned)f2bf(b) << 16);
}

// in-register C->B relayout, 2 bpermutes/kb (select-before-permute):
// lo lane needs partner's A0/A1; hi lane needs partner's B0/B1 -> source lane
// sends (hi ? A : B).
template<bool RELU>
__device__ __forceinline__ void relayout32(f32x16 (&acc)[2], s16x8 (&bout)[4],
                                           int bpidx, int hi)
{
    if (RELU) {
#pragma unroll
        for (int t = 0; t < 2; ++t)
#pragma unroll
            for (int i = 0; i < 16; ++i) acc[t][i] = fmaxf(acc[t][i], 0.f);
    }
#pragma unroll
    for (int kb = 0; kb < 4; ++kb) {
        int m0 = 2 * kb, m1 = 2 * kb + 1;
        int t0 = m0 >> 2, g0 = m0 & 3, t1 = m1 >> 2, g1 = m1 & 3;
        unsigned A0 = pk2(acc[t0][4 * g0 + 0], acc[t0][4 * g0 + 1]);
        unsigned A1 = pk2(acc[t0][4 * g0 + 2], acc[t0][4 * g0 + 3]);
        unsigned B0 = pk2(acc[t1][4 * g1 + 0], acc[t1][4 * g1 + 1]);
        unsigned B1 = pk2(acc[t1][4 * g1 + 2], acc[t1][4 * g1 + 3]);
        unsigned s0 = hi ? A0 : B0;
        unsigned s1 = hi ? A1 : B1;
        unsigned p0 = (unsigned)__builtin_amdgcn_ds_bpermute(bpidx, (int)s0);
        unsigned p1 = (unsigned)__builtin_amdgcn_ds_bpermute(bpidx, (int)s1);
        union { unsigned w[4]; s16x8 v; } u;
        u.w[0] = hi ? p0 : A0;
        u.w[1] = hi ? p1 : A1;
        u.w[2] = hi ? B0 : p0;
        u.w[3] = hi ? B1 : p1;
        bout[kb] = u.v;
    }
}

__device__ __forceinline__ void store32(const f32x16 (&acc)[2],
                                        unsigned short* __restrict__ dst, int hi)
{
#pragma unroll
    for (int t = 0; t < 2; ++t)
#pragma unroll
        for (int g = 0; g < 4; ++g) {
            u16x4 p;
#pragma unroll
            for (int r = 0; r < 4; ++r) p[r] = f2bf(acc[t][4 * g + r]);
            *(u16x4*)(dst + 32 * t + 8 * g + 4 * hi) = p;
        }
}

// single-tile layer (clause): weights in swizzled LDS unit, bias in LDS
__device__ __forceinline__ void layer32(const char* __restrict__ unitBase,
                                        const float* __restrict__ biasL,
                                        const s16x8 (&bin)[4], f32x16 (&acc)[2],
                                        int eL, int hi)
{
#pragma unroll
    for (int t = 0; t < 2; ++t)
#pragma unroll
        for (int g = 0; g < 4; ++g) {
            f32x4 bv = *(const f32x4*)(biasL + 32 * t + 8 * g + 4 * hi);
#pragma unroll
            for (int r = 0; r < 4; ++r) acc[t][4 * g + r] = bv[r];
        }
#pragma unroll
    for (int kb = 0; kb < 4; ++kb)
#pragma unroll
        for (int t = 0; t < 2; ++t) {
            int row = 32 * t + eL;
            s16x8 a = *(const s16x8*)(unitBase + row * 128 +
                                      ((32 * kb + 16 * hi) ^ ((row & 7) << 4)));
            acc[t] = mfma32(a, bin[kb], acc[t]);
        }
}

// dual-tile layer (lit): one A-fragment read feeds 2 independent MFMAs
__device__ __forceinline__ void layer32x2(const char* __restrict__ unitBase,
                                          const float* __restrict__ biasL,
                                          const s16x8 (&b0)[4], const s16x8 (&b1)[4],
                                          f32x16 (&acc0)[2], f32x16 (&acc1)[2],
                                          int eL, int hi)
{
#pragma unroll
    for (int t = 0; t < 2; ++t)
#pragma unroll
        for (int g = 0; g < 4; ++g) {
            f32x4 bv = *(const f32x4*)(biasL + 32 * t + 8 * g + 4 * hi);
#pragma unroll
            for (int r = 0; r < 4; ++r) { acc0[t][4 * g + r] = bv[r]; acc1[t][4 * g + r] = bv[r]; }
        }
#pragma unroll
    for (int kb = 0; kb < 4; ++kb)
#pragma unroll
        for (int t = 0; t < 2; ++t) {
            int row = 32 * t + eL;
            s16x8 a = *(const s16x8*)(unitBase + row * 128 +
                                      ((32 * kb + 16 * hi) ^ ((row & 7) << 4)));
            acc0[t] = mfma32(a, b0[kb], acc0[t]);
            acc1[t] = mfma32(a, b1[kb], acc1[t]);
        }
}

// -------- transpose + bf16 + PRE-SWIZZLE all round weights into unit layout --------
__global__ __launch_bounds__(256) void prep_weights(
    const float* __restrict__ msgl_W, const float* __restrict__ merge_W0,
    const float* __restrict__ merge_Wr, const float* __restrict__ msgc_W,
    unsigned short* __restrict__ wT)
{
    int gid = blockIdx.x * 256 + threadIdx.x;
    if (gid >= WT_TOTAL) return;
    int unit = gid >> 12;
    int o = (gid >> 6) & 63;              // row = out
    int csw = gid & 63;
    int i = csw ^ ((o & 7) << 3);         // col = in (un-swizzled)
    float v;
    if (unit < 3)       v = msgl_W[unit * 4096 + i * 64 + o];
    else if (unit < 5)  v = merge_W0[((unit - 3) * 64 + i) * 64 + o];
    else if (unit < 7)  v = merge_Wr[(unit - 5) * 4096 + i * 64 + o];
    else                v = msgc_W[(unit - 7) * 4096 + i * 64 + o];
    wT[gid] = f2bf(v);
}

// -------- CSR build: histogram -> 3-stage parallel scan -> scatter --------
__global__ __launch_bounds__(256) void csr_hist(const int* __restrict__ lit_idx,
                                                int* __restrict__ cnt)
{
    int e = blockIdx.x * 256 + threadIdx.x;
    if (e < EDGES) atomicAdd(&cnt[lit_idx[e]], 1);
}

__global__ __launch_bounds__(256) void scan1(const int* __restrict__ cnt,
                                             int* __restrict__ bsum)
{
    __shared__ int red[4];
    int i = blockIdx.x * 256 + threadIdx.x;
    int s = (i < NLIT) ? cnt[i] : 0;
#pragma unroll
    for (int off = 1; off < 64; off <<= 1) s += __shfl_xor(s, off, 64);
    if ((threadIdx.x & 63) == 0) red[threadIdx.x >> 6] = s;
    __syncthreads();
    if (threadIdx.x == 0) bsum[blockIdx.x] = red[0] + red[1] + red[2] + red[3];
}

__global__ __launch_bounds__(256) void scan2(const int* __restrict__ bsum,
                                             int* __restrict__ bbase)
{
    __shared__ int tmp[256];
    int t = threadIdx.x;
    int v = (t < SCAN_BLOCKS) ? bsum[t] : 0;
    tmp[t] = v;
    __syncthreads();
#pragma unroll
    for (int off = 1; off < 256; off <<= 1) {
        int add = (t >= off) ? tmp[t - off] : 0;
        __syncthreads();
        tmp[t] += add;
        __syncthreads();
    }
    if (t < SCAN_BLOCKS) bbase[t] = tmp[t] - v;   // exclusive
}

__global__ __launch_bounds__(256) void scan3(const int* __restrict__ cnt,
                                             const int* __restrict__ bbase,
                                             int* __restrict__ off,
                                             int* __restrict__ cursor)
{
    __shared__ int tmp[256];
    int t = threadIdx.x;
    int i = blockIdx.x * 256 + t;
    int v = (i < NLIT) ? cnt[i] : 0;
    tmp[t] = v;
    __syncthreads();
#pragma unroll
    for (int offs = 1; offs < 256; offs <<= 1) {
        int add = (t >= offs) ? tmp[t - offs] : 0;
        __syncthreads();
        tmp[t] += add;
        __syncthreads();
    }
    if (i < NLIT) {
        int ex = bbase[blockIdx.x] + tmp[t] - v;
        off[i] = ex; cursor[i] = ex;
    }
    if (i == NLIT - 1) off[NLIT] = EDGES;
}

__global__ __launch_bounds__(256) void csr_scatter(const int* __restrict__ lit_idx,
                                                   int* __restrict__ cursor,
                                                   int* __restrict__ eidx)
{
    int e = blockIdx.x * 256 + threadIdx.x;
    if (e >= EDGES) return;
    int pos = atomicAdd(&cursor[lit_idx[e]], 1);
    eidx[pos] = e;
}

// -------- gather aggregation, group-of-4 latency breaking --------
__global__ __launch_bounds__(256) void aggregate(const unsigned short* __restrict__ h_c2l,
                                                 const int* __restrict__ off,
                                                 const int* __restrict__ eidx,
                                                 float* __restrict__ agg)
{
    int t = threadIdx.x;
    int lane8 = t & 7;
    int lit = blockIdx.x * 32 + (t >> 3);
    if (lit >= NLIT) return;
    int lo = off[lit], hi = off[lit + 1];
    float s[8] = {0, 0, 0, 0, 0, 0, 0, 0};
    int i = lo;
    for (; i + 4 <= hi; i += 4) {
        int e0 = eidx[i], e1 = eidx[i + 1], e2 = eidx[i + 2], e3 = eidx[i + 3];
        u16x8 v0 = *(const u16x8*)(h_c2l + e0 * 64 + lane8 * 8);
        u16x8 v1 = *(const u16x8*)(h_c2l + e1 * 64 + lane8 * 8);
        u16x8 v2 = *(const u16x8*)(h_c2l + e2 * 64 + lane8 * 8);
        u16x8 v3 = *(const u16x8*)(h_c2l + e3 * 64 + lane8 * 8);
#pragma unroll
        for (int j = 0; j < 8; ++j)
            s[j] += (bf2f(v0[j]) + bf2f(v1[j])) + (bf2f(v2[j]) + bf2f(v3[j]));
    }
    for (; i < hi; ++i) {
        int e = eidx[i];
        u16x8 hv = *(const u16x8*)(h_c2l + e * 64 + lane8 * 8);
#pragma unroll
        for (int j = 0; j < 8; ++j) s[j] += bf2f(hv[j]);
    }
    f32x4 a0, a1;
    a0[0] = s[0]; a0[1] = s[1]; a0[2] = s[2]; a0[3] = s[3];
    a1[0] = s[4]; a1[1] = s[5]; a1[2] = s[6]; a1[3] = s[7];
    *(f32x4*)(agg + lit * 64 + lane8 * 8)     = a0;
    *(f32x4*)(agg + lit * 64 + lane8 * 8 + 4) = a1;
}

// -------- init: h = feat @ W_init + b  (bf16) --------
__global__ __launch_bounds__(256) void init_kernel(
    const float* __restrict__ feat_l2c, const float* __restrict__ feat_c2l,
    const float* __restrict__ W_l2c, const float* __restrict__ b_l2c,
    const float* __restrict__ W_c2l, const float* __restrict__ b_c2l,
    unsigned short* __restrict__ h_l2c, unsigned short* __restrict__ h_c2l)
{
    int gid = blockIdx.x * 256 + threadIdx.x;
    if (gid >= EDGES * 8) return;
    int e = gid >> 3, fo = (gid & 7) << 3;
    float2 fl = *(const float2*)(feat_l2c + e * 2);
    float2 fc = *(const float2*)(feat_c2l + e * 2);

    u16x8 outl, outc;
#pragma unroll
    for (int j = 0; j < 8; ++j) {
        float wl0 = W_l2c[fo + j], wl1 = W_l2c[64 + fo + j];
        float wc0 = W_c2l[fo + j], wc1 = W_c2l[64 + fo + j];
        float vl = fl.x * wl0 + fl.y * wl1 + b_l2c[fo + j];
        float vc = fc.x * wc0 + fc.y * wc1 + b_c2l[fo + j];
        outl[j] = f2bf(vl);
        outc[j] = f2bf(vc);
    }
    *(u16x8*)(h_l2c + e * 64 + fo) = outl;
    *(u16x8*)(h_c2l + e * 64 + fo) = outc;
}

// -------- literal update: 2 chunks/wave; x0=(agg-h)/8 -> MLP3 -> merge -> h_l2c --------
__global__ __launch_bounds__(512, 3) void lit_update(
    const unsigned short* __restrict__ h_c2l,
    unsigned short* __restrict__ h_l2c,
    const float* __restrict__ agg,
    const int* __restrict__ lit_idx,
    const unsigned short* __restrict__ wT,
    const float* __restrict__ msgl_b,
    const float* __restrict__ merge_b0,
    const float* __restrict__ merge_br)
{
    __shared__ __align__(16) char lds[LIT_WBYTES + 384 * 4];   // 58880 B -> 2 blocks/CU
    int tid = threadIdx.x;
#pragma unroll
    for (int c = 0; c < 7; ++c) {
        int idx = c * 512 + tid;
        *(u16x8*)(lds + idx * 16) = *(const u16x8*)(wT + idx * 8);
    }
    float* ldsBias = (float*)(lds + LIT_WBYTES);
    if (tid < 384) {
        float v;
        if (tid < 192)      v = msgl_b[tid];
        else if (tid < 256) v = merge_b0[tid - 192];
        else                v = merge_br[tid - 256];
        ldsBias[tid] = v;
    }
    __syncthreads();

    int wv = tid >> 6, lane = tid & 63;
    int eL = lane & 31, hi = lane >> 5;
    int bpidx = (lane ^ 32) << 2;
    int base = blockIdx.x * LIT_EPB + wv * 64;
    if (base >= EDGES) return;
    bool has2 = (base + 32) < EDGES;
    int e0 = base + eL;
    int e1 = has2 ? (base + 32 + eL) : e0;
    int l0 = lit_idx[e0];
    int l1 = lit_idx[e1];

    // old h_l2c fragments (merge kb 4-7) -- load early, hide under msgl layers
    s16x8 hfragA[4], hfragB[4];
#pragma unroll
    for (int k = 0; k < 4; ++k) {
        hfragA[k] = *(const s16x8*)(h_l2c + e0 * 64 + 16 * k + 8 * hi);
        hfragB[k] = *(const s16x8*)(h_l2c + e1 * 64 + 16 * k + 8 * hi);
    }

    // input x0 fragments
    s16x8 bfA[4], bfB[4];
#pragma unroll
    for (int k = 0; k < 4; ++k) {
        int f0 = 16 * k + 8 * hi;
        f32x4 a0 = *(const f32x4*)(agg + l0 * 64 + f0);
        f32x4 a1 = *(const f32x4*)(agg + l0 * 64 + f0 + 4);
        u16x8 hv = *(const u16x8*)(h_c2l + e0 * 64 + f0);
        s16x8 b;
#pragma unroll
        for (int j = 0; j < 4; ++j) b[j]     = (short)f2bf((a0[j] - bf2f(hv[j]))     * 0.125f);
#pragma unroll
        for (int j = 0; j < 4; ++j) b[4 + j] = (short)f2bf((a1[j] - bf2f(hv[4 + j])) * 0.125f);
        bfA[k] = b;
        f32x4 c0 = *(const f32x4*)(agg + l1 * 64 + f0);
        f32x4 c1 = *(const f32x4*)(agg + l1 * 64 + f0 + 4);
        u16x8 hw = *(const u16x8*)(h_c2l + e1 * 64 + f0);
#pragma unroll
        for (int j = 0; j < 4; ++j) b[j]     = (short)f2bf((c0[j] - bf2f(hw[j]))     * 0.125f);
#pragma unroll
        for (int j = 0; j < 4; ++j) b[4 + j] = (short)f2bf((c1[j] - bf2f(hw[4 + j])) * 0.125f);
        bfB[k] = b;
    }

    f32x16 accA[2], accB[2];
    layer32x2(lds,            ldsBias,       bfA, bfB, accA, accB, eL, hi);
    relayout32<true >(accA, bfA, bpidx, hi);
    relayout32<true >(accB, bfB, bpidx, hi);
    layer32x2(lds + 8192,     ldsBias + 64,  bfA, bfB, accA, accB, eL, hi);
    relayout32<true >(accA, bfA, bpidx, hi);
    relayout32<true >(accB, bfB, bpidx, hi);
    layer32x2(lds + 2 * 8192, ldsBias + 128, bfA, bfB, accA, accB, eL, hi);
    relayout32<false>(accA, bfA, bpidx, hi);   // m fragments
    relayout32<false>(accB, bfB, bpidx, hi);

    // merge layer 0: K=128 = [m | h_old], units 3 (m) and 4 (h)
#pragma unroll
    for (int t = 0; t < 2; ++t)
#pragma unroll
        for (int g = 0; g < 4; ++g) {
            f32x4 bv = *(const f32x4*)(ldsBias + 192 + 32 * t + 8 * g + 4 * hi);
#pragma unroll
            for (int r = 0; r < 4; ++r) { accA[t][4 * g + r] = bv[r]; accB[t][4 * g + r] = bv[r]; }
        }
#pragma unroll
    for (int kb = 0; kb < 8; ++kb) {
        const char* ub = lds + (3 + (kb >> 2)) * 8192;
        s16x8 bA = (kb < 4) ? bfA[kb] : hfragA[kb - 4];
        s16x8 bB = (kb < 4) ? bfB[kb] : hfragB[kb - 4];
#pragma unroll
        for (int t = 0; t < 2; ++t) {
            int row = 32 * t + eL;
            s16x8 a = *(const s16x8*)(ub + row * 128 +
                                      ((32 * (kb & 3) + 16 * hi) ^ ((row & 7) << 4)));
            accA[t] = mfma32(a, bA, accA[t]);
            accB[t] = mfma32(a, bB, accB[t]);
        }
    }
    relayout32<true>(accA, bfA, bpidx, hi);
    relayout32<true>(accB, bfB, bpidx, hi);
    layer32x2(lds + 5 * 8192, ldsBias + 256, bfA, bfB, accA, accB, eL, hi);
    relayout32<true>(accA, bfA, bpidx, hi);
    relayout32<true>(accB, bfB, bpidx, hi);
    layer32x2(lds + 6 * 8192, ldsBias + 320, bfA, bfB, accA, accB, eL, hi);

    store32(accA, h_l2c + e0 * 64, hi);
    if (has2) store32(accB, h_l2c + e1 * 64, hi);
}

// -------- clause update: x0=(sum of 2 siblings)/8 -> MLP3 -> h_c2l --------
__global__ __launch_bounds__(512, 4) void clause_update(
    const unsigned short* __restrict__ h_l2c,
    unsigned short* __restrict__ h_c2l,
    const unsigned short* __restrict__ msgcT,
    const float* __restrict__ msgc_b)
{
    __shared__ __align__(16) char lds[CLS_WBYTES + 192 * 4];   // 25344 B
    int tid = threadIdx.x;
#pragma unroll
    for (int c = 0; c < 3; ++c) {
        int idx = c * 512 + tid;
        *(u16x8*)(lds + idx * 16) = *(const u16x8*)(msgcT + idx * 8);
    }
    float* ldsBias = (float*)(lds + CLS_WBYTES);
    if (tid < 192) ldsBias[tid] = msgc_b[tid];
    __syncthreads();

    int wv = tid >> 6, lane = tid & 63;
    int eL = lane & 31, hi = lane >> 5;
    int bpidx = (lane ^ 32) << 2;
    int base = blockIdx.x * CLS_EPB + wv * 32;
    if (base >= EDGES) return;
    int e = base + eL;

    int c3 = (e / 3) * 3;
    int d = e - c3;
    int e1 = c3 + (d == 0 ? 1 : 0);
    int e2 = c3 + (d == 2 ? 1 : 2);

    s16x8 binp[4];
#pragma unroll
    for (int k = 0; k < 4; ++k) {
        int f0 = 16 * k + 8 * hi;
        u16x8 h1 = *(const u16x8*)(h_l2c + e1 * 64 + f0);
        u16x8 h2 = *(const u16x8*)(h_l2c + e2 * 64 + f0);
        s16x8 b;
#pragma unroll
        for (int j = 0; j < 8; ++j)
            b[j] = (short)f2bf((bf2f(h1[j]) + bf2f(h2[j])) * 0.125f);
        binp[k] = b;
    }

    f32x16 acc[2];
    s16x8 bf[4];
    layer32(lds,            ldsBias,       binp, acc, eL, hi);
    relayout32<true>(acc, bf, bpidx, hi);
    layer32(lds + 8192,     ldsBias + 64,  bf, acc, eL, hi);
    relayout32<true>(acc, bf, bpidx, hi);
    layer32(lds + 2 * 8192, ldsBias + 128, bf, acc, eL, hi);

    store32(acc, h_c2l + e * 64, hi);
}

// -------- readout stage 1: per-graph sum of h_c2l over contiguous 75000 edges --------
__global__ __launch_bounds__(256) void readout_sum(
    const unsigned short* __restrict__ h_c2l, float* __restrict__ ro_acc)
{
    __shared__ float lsum[32][64];
    int g = blockIdx.x >> 6, chunk = blockIdx.x & 63;
    int t = threadIdx.x;
    int fg = t & 7, el = t >> 3;
    float s[8] = {0, 0, 0, 0, 0, 0, 0, 0};
    for (int idx = chunk * 32 + el; idx < EPG; idx += 2048) {
        u16x8 hv = *(const u16x8*)(h_c2l + (g * EPG + idx) * 64 + fg * 8);
#pragma unroll
        for (int j = 0; j < 8; ++j) s[j] += bf2f(hv[j]);
    }
#pragma unroll
    for (int j = 0; j < 8; ++j) lsum[el][fg * 8 + j] = s[j];
    __syncthreads();
    if (t < 64) {
        float tot = 0.f;
#pragma unroll 8
        for (int r = 0; r < 32; ++r) tot += lsum[r][t];
        atomicAdd(&ro_acc[g * 64 + t], tot);
    }
}

// -------- readout stage 2: tiny MLP + sigmoid --------
__global__ __launch_bounds__(256) void readout_mlp(
    const float* __restrict__ ro_acc, const float* __restrict__ ro_W,
    const float* __restrict__ ro_b, const float* __restrict__ ro_W2,
    const float* __restrict__ ro_b2, float* __restrict__ out)
{
    __shared__ float xb[NGRAPH][HDIM];
    __shared__ float yb[NGRAPH][HDIM];
    int g = threadIdx.x >> 6;
    int j = threadIdx.x & 63;
    xb[g][j] = ro_acc[g * HDIM + j] * (1.0f / 12500.0f);
    __syncthreads();
    float a = ro_b[j];
#pragma unroll 8
    for (int k = 0; k < HDIM; ++k) a += xb[g][k] * ro_W[k * HDIM + j];
    a = fmaxf(a, 0.0f);
    yb[g][j] = a;
    __syncthreads();
    float a2 = ro_b[HDIM + j];
#pragma unroll 8
    for (int k = 0; k < HDIM; ++k) a2 += yb[g][k] * ro_W[4096 + k * HDIM + j];
    a2 = fmaxf(a2, 0.0f);
    float p = a2 * ro_W2[j];
#pragma unroll
    for (int off = 32; off > 0; off >>= 1) p += __shfl_down(p, off, 64);
    if (j == 0) out[g] = 1.0f / (1.0f + expf(-(p + ro_b2[0])));
}

extern "C" void kernel_launch(void* const* d_in, const int* in_sizes, int n_in,
                              void* d_out, int out_size, void* d_ws, size_t ws_size,
                              hipStream_t stream)
{
    const float* feat_l2c = (const float*)d_in[0];
    const float* feat_c2l = (const float*)d_in[1];
    const int*   lit_idx  = (const int*)d_in[2];
    // d_in[3] (cls_idx) unused: edges are clause-major by construction
    const float* W_l2c    = (const float*)d_in[4];
    const float* b_l2c    = (const float*)d_in[5];
    const float* W_c2l    = (const float*)d_in[6];
    const float* b_c2l    = (const float*)d_in[7];
    const float* msgl_W   = (const float*)d_in[8];
    const float* msgl_b   = (const float*)d_in[9];
    const float* merge_W0 = (const float*)d_in[10];
    const float* merge_b0 = (const float*)d_in[11];
    const float* merge_Wr = (const float*)d_in[12];
    const float* merge_br = (const float*)d_in[13];
    const float* msgc_W   = (const float*)d_in[14];
    const float* msgc_b   = (const float*)d_in[15];
    const float* ro_W     = (const float*)d_in[16];
    const float* ro_b     = (const float*)d_in[17];
    const float* ro_W2    = (const float*)d_in[18];
    const float* ro_b2    = (const float*)d_in[19];

    char* ws = (char*)d_ws;
    unsigned short* h_l2c  = (unsigned short*)(ws + OFF_HL2C);
    unsigned short* h_c2l  = (unsigned short*)(ws + OFF_HC2L);
    float*          agg    = (float*)(ws + OFF_AGG);
    unsigned short* wT     = (unsigned short*)(ws + OFF_WT);
    float*          ro_acc = (float*)(ws + OFF_ROACC);
    int*            cnt    = (int*)(ws + OFF_CNT);
    int*            csroff = (int*)(ws + OFF_CSROFF);
    int*            cursor = (int*)(ws + OFF_CURSOR);
    int*            eidx   = (int*)(ws + OFF_EIDX);
    int*            bsum   = (int*)(ws + OFF_BSUM);
    int*            bbase  = (int*)(ws + OFF_BBASE);

    hipMemsetAsync(cnt, 0, NLIT * sizeof(int), stream);
    hipMemsetAsync(ro_acc, 0, NGRAPH * 64 * sizeof(float), stream);

    prep_weights<<<(WT_TOTAL + 255) / 256, 256, 0, stream>>>(msgl_W, merge_W0, merge_Wr, msgc_W, wT);

    // CSR of lit_idx (per-launch rebuild; 3-stage parallel scan)
    csr_hist<<<(EDGES + 255) / 256, 256, 0, stream>>>(lit_idx, cnt);
    scan1<<<SCAN_BLOCKS, 256, 0, stream>>>(cnt, bsum);
    scan2<<<1, 256, 0, stream>>>(bsum, bbase);
    scan3<<<SCAN_BLOCKS, 256, 0, stream>>>(cnt, bbase, csroff, cursor);
    csr_scatter<<<(EDGES + 255) / 256, 256, 0, stream>>>(lit_idx, cursor, eidx);

    init_kernel<<<EDGES * 8 / 256, 256, 0, stream>>>(feat_l2c, feat_c2l, W_l2c, b_l2c,
                                                     W_c2l, b_c2l, h_l2c, h_c2l);
    for (int r = 0; r < 3; ++r) {
        aggregate<<<(NLIT + 31) / 32, 256, 0, stream>>>(h_c2l, csroff, eidx, agg);
        lit_update<<<LIT_GRID, 512, 0, stream>>>(h_c2l, h_l2c, agg, lit_idx, wT,
                                                 msgl_b, merge_b0, merge_br);
        clause_update<<<CLS_GRID, 512, 0, stream>>>(h_l2c, h_c2l, wT + WT_CLS_ELEM, msgc_b);
    }
    readout_sum<<<256, 256, 0, stream>>>(h_c2l, ro_acc);
    readout_mlp<<<1, 256, 0, stream>>>(ro_acc, ro_W, ro_b, ro_W2, ro_b2, (float*)d_out);
}

// Round 11
// 324.776 us; speedup vs baseline: 1.3897x; 1.1651x over previous
//
#include <hip/hip_runtime.h>
#include <hip/hip_bf16.h>
#include <stdint.h>

// ---------------- problem constants ----------------
#define EDGES   300000
#define NLIT    50000
#define NGRAPH  4
#define EPG     75000          // edges per graph (contiguous)
#define HDIM    64

// ws layout (bytes)
#define OFF_HL2C   0
#define OFF_HC2L   38400000
#define OFF_AGG    76800000
#define OFF_WT     89600000
#define OFF_ROACC  89681920
#define OFF_CNT    89682944
#define OFF_CSROFF 89882944
#define OFF_CURSOR 90082948
#define OFF_EIDX   90282948
#define OFF_BSUM   91482948
#define OFF_BBASE  91484000

// wT global layout: 10 "units", each [64 rows=out][64 cols=in] bf16 (4096 elems),
// stored PRE-SWIZZLED: element (u,row,col) at u*4096 + row*64 + (col ^ ((row&7)<<3)).
// u0-2: msglT ; u3: merge0T cols 0-63 (m part) ; u4: merge0T cols 64-127 (h part)
// u5-6: mergeRT ; u7-9: msgcT
#define WT_TOTAL    40960
#define WT_CLS_ELEM 28672      // element offset of clause units (u7)

#define LIT_WBYTES (7 * 8192)   // 57344
#define CLS_WBYTES (3 * 8192)   // 24576
#define EPB2       256          // edges per block (8 waves x 32)
#define GRID_EDGE  ((EDGES + EPB2 - 1) / EPB2)   // 1172

#define SCAN_BLOCKS ((NLIT + 255) / 256)   // 196

typedef __attribute__((ext_vector_type(8)))  short          s16x8;
typedef __attribute__((ext_vector_type(8)))  unsigned short u16x8;
typedef __attribute__((ext_vector_type(4)))  unsigned short u16x4;
typedef __attribute__((ext_vector_type(4)))  float          f32x4;
typedef __attribute__((ext_vector_type(16))) float          f32x16;

__device__ __forceinline__ f32x16 mfma32(s16x8 a, s16x8 b, f32x16 c) {
    return __builtin_amdgcn_mfma_f32_32x32x16_bf16(a, b, c, 0, 0, 0);
}
__device__ __forceinline__ float bf2f(unsigned short s) {
    union { unsigned int u; float f; } v; v.u = ((unsigned int)s) << 16; return v.f;
}
// native RNE convert (compiler emits v_cvt_pk_bf16_f32 for pairs)
__device__ __forceinline__ unsigned short f2bf(float f) {
    union { __hip_bfloat16 b; unsigned short s; } v;
    v.b = __float2bfloat16(f);
    return v.s;
}
__device__ __forceinline__ unsigned pk2(float a, float b) {
    return (unsigned)f2bf(a) | ((unsigned)f2bf(b) << 16);
}

// in-register C->B relayout, 2 bpermutes/kb (select-before-permute), HW-verified R10
template<bool RELU>
__device__ __forceinline__ void relayout32(f32x16 (&acc)[2], s16x8 (&bout)[4],
                                           int bpidx, int hi)
{
    if (RELU) {
#pragma unroll
        for (int t = 0; t < 2; ++t)
#pragma unroll
            for (int i = 0; i < 16; ++i) acc[t][i] = fmaxf(acc[t][i], 0.f);
    }
#pragma unroll
    for (int kb = 0; kb < 4; ++kb) {
        int m0 = 2 * kb, m1 = 2 * kb + 1;
        int t0 = m0 >> 2, g0 = m0 & 3, t1 = m1 >> 2, g1 = m1 & 3;
        unsigned A0 = pk2(acc[t0][4 * g0 + 0], acc[t0][4 * g0 + 1]);
        unsigned A1 = pk2(acc[t0][4 * g0 + 2], acc[t0][4 * g0 + 3]);
        unsigned B0 = pk2(acc[t1][4 * g1 + 0], acc[t1][4 * g1 + 1]);
        unsigned B1 = pk2(acc[t1][4 * g1 + 2], acc[t1][4 * g1 + 3]);
        unsigned s0 = hi ? A0 : B0;
        unsigned s1 = hi ? A1 : B1;
        unsigned p0 = (unsigned)__builtin_amdgcn_ds_bpermute(bpidx, (int)s0);
        unsigned p1 = (unsigned)__builtin_amdgcn_ds_bpermute(bpidx, (int)s1);
        union { unsigned w[4]; s16x8 v; } u;
        u.w[0] = hi ? p0 : A0;
        u.w[1] = hi ? p1 : A1;
        u.w[2] = hi ? B0 : p0;
        u.w[3] = hi ? B1 : p1;
        bout[kb] = u.v;
    }
}

__device__ __forceinline__ void store32(const f32x16 (&acc)[2],
                                        unsigned short* __restrict__ dst, int hi)
{
#pragma unroll
    for (int t = 0; t < 2; ++t)
#pragma unroll
        for (int g = 0; g < 4; ++g) {
            u16x4 p;
#pragma unroll
            for (int r = 0; r < 4; ++r) p[r] = f2bf(acc[t][4 * g + r]);
            *(u16x4*)(dst + 32 * t + 8 * g + 4 * hi) = p;
        }
}

// one 64->64 layer, 32x32x16 MFMA, weights in swizzled LDS unit, bias in LDS
__device__ __forceinline__ void layer32(const char* __restrict__ unitBase,
                                        const float* __restrict__ biasL,
                                        const s16x8 (&bin)[4], f32x16 (&acc)[2],
                                        int eL, int hi)
{
#pragma unroll
    for (int t = 0; t < 2; ++t)
#pragma unroll
        for (int g = 0; g < 4; ++g) {
            f32x4 bv = *(const f32x4*)(biasL + 32 * t + 8 * g + 4 * hi);
#pragma unroll
            for (int r = 0; r < 4; ++r) acc[t][4 * g + r] = bv[r];
        }
#pragma unroll
    for (int kb = 0; kb < 4; ++kb)
#pragma unroll
        for (int t = 0; t < 2; ++t) {
            int row = 32 * t + eL;
            s16x8 a = *(const s16x8*)(unitBase + row * 128 +
                                      ((32 * kb + 16 * hi) ^ ((row & 7) << 4)));
            acc[t] = mfma32(a, bin[kb], acc[t]);
        }
}

// -------- transpose + bf16 + PRE-SWIZZLE all round weights into unit layout --------
__global__ __launch_bounds__(256) void prep_weights(
    const float* __restrict__ msgl_W, const float* __restrict__ merge_W0,
    const float* __restrict__ merge_Wr, const float* __restrict__ msgc_W,
    unsigned short* __restrict__ wT)
{
    int gid = blockIdx.x * 256 + threadIdx.x;
    if (gid >= WT_TOTAL) return;
    int unit = gid >> 12;
    int o = (gid >> 6) & 63;              // row = out
    int csw = gid & 63;
    int i = csw ^ ((o & 7) << 3);         // col = in (un-swizzled)
    float v;
    if (unit < 3)       v = msgl_W[unit * 4096 + i * 64 + o];
    else if (unit < 5)  v = merge_W0[((unit - 3) * 64 + i) * 64 + o];
    else if (unit < 7)  v = merge_Wr[(unit - 5) * 4096 + i * 64 + o];
    else                v = msgc_W[(unit - 7) * 4096 + i * 64 + o];
    wT[gid] = f2bf(v);
}

// -------- CSR build: histogram -> 3-stage parallel scan -> scatter --------
__global__ __launch_bounds__(256) void csr_hist(const int* __restrict__ lit_idx,
                                                int* __restrict__ cnt)
{
    int e = blockIdx.x * 256 + threadIdx.x;
    if (e < EDGES) atomicAdd(&cnt[lit_idx[e]], 1);
}

__global__ __launch_bounds__(256) void scan1(const int* __restrict__ cnt,
                                             int* __restrict__ bsum)
{
    __shared__ int red[4];
    int i = blockIdx.x * 256 + threadIdx.x;
    int s = (i < NLIT) ? cnt[i] : 0;
#pragma unroll
    for (int off = 1; off < 64; off <<= 1) s += __shfl_xor(s, off, 64);
    if ((threadIdx.x & 63) == 0) red[threadIdx.x >> 6] = s;
    __syncthreads();
    if (threadIdx.x == 0) bsum[blockIdx.x] = red[0] + red[1] + red[2] + red[3];
}

__global__ __launch_bounds__(256) void scan2(const int* __restrict__ bsum,
                                             int* __restrict__ bbase)
{
    __shared__ int tmp[256];
    int t = threadIdx.x;
    int v = (t < SCAN_BLOCKS) ? bsum[t] : 0;
    tmp[t] = v;
    __syncthreads();
#pragma unroll
    for (int off = 1; off < 256; off <<= 1) {
        int add = (t >= off) ? tmp[t - off] : 0;
        __syncthreads();
        tmp[t] += add;
        __syncthreads();
    }
    if (t < SCAN_BLOCKS) bbase[t] = tmp[t] - v;   // exclusive
}

__global__ __launch_bounds__(256) void scan3(const int* __restrict__ cnt,
                                             const int* __restrict__ bbase,
                                             int* __restrict__ off,
                                             int* __restrict__ cursor)
{
    __shared__ int tmp[256];
    int t = threadIdx.x;
    int i = blockIdx.x * 256 + t;
    int v = (i < NLIT) ? cnt[i] : 0;
    tmp[t] = v;
    __syncthreads();
#pragma unroll
    for (int offs = 1; offs < 256; offs <<= 1) {
        int add = (t >= offs) ? tmp[t - offs] : 0;
        __syncthreads();
        tmp[t] += add;
        __syncthreads();
    }
    if (i < NLIT) {
        int ex = bbase[blockIdx.x] + tmp[t] - v;
        off[i] = ex; cursor[i] = ex;
    }
    if (i == NLIT - 1) off[NLIT] = EDGES;
}

__global__ __launch_bounds__(256) void csr_scatter(const int* __restrict__ lit_idx,
                                                   int* __restrict__ cursor,
                                                   int* __restrict__ eidx)
{
    int e = blockIdx.x * 256 + threadIdx.x;
    if (e >= EDGES) return;
    int pos = atomicAdd(&cursor[lit_idx[e]], 1);
    eidx[pos] = e;
}

// -------- gather aggregation (bf16 output), group-of-4 latency breaking --------
__global__ __launch_bounds__(256) void aggregate(const unsigned short* __restrict__ h_c2l,
                                                 const int* __restrict__ off,
                                                 const int* __restrict__ eidx,
                                                 unsigned short* __restrict__ agg)
{
    int t = threadIdx.x;
    int lane8 = t & 7;
    int lit = blockIdx.x * 32 + (t >> 3);
    if (lit >= NLIT) return;
    int lo = off[lit], hi = off[lit + 1];
    float s[8] = {0, 0, 0, 0, 0, 0, 0, 0};
    int i = lo;
    for (; i + 4 <= hi; i += 4) {
        int e0 = eidx[i], e1 = eidx[i + 1], e2 = eidx[i + 2], e3 = eidx[i + 3];
        u16x8 v0 = *(const u16x8*)(h_c2l + e0 * 64 + lane8 * 8);
        u16x8 v1 = *(const u16x8*)(h_c2l + e1 * 64 + lane8 * 8);
        u16x8 v2 = *(const u16x8*)(h_c2l + e2 * 64 + lane8 * 8);
        u16x8 v3 = *(const u16x8*)(h_c2l + e3 * 64 + lane8 * 8);
#pragma unroll
        for (int j = 0; j < 8; ++j)
            s[j] += (bf2f(v0[j]) + bf2f(v1[j])) + (bf2f(v2[j]) + bf2f(v3[j]));
    }
    for (; i < hi; ++i) {
        int e = eidx[i];
        u16x8 hv = *(const u16x8*)(h_c2l + e * 64 + lane8 * 8);
#pragma unroll
        for (int j = 0; j < 8; ++j) s[j] += bf2f(hv[j]);
    }
    u16x8 o;
#pragma unroll
    for (int j = 0; j < 8; ++j) o[j] = f2bf(s[j]);
    *(u16x8*)(agg + lit * 64 + lane8 * 8) = o;
}

// -------- init: h = feat @ W_init + b  (bf16) --------
__global__ __launch_bounds__(256) void init_kernel(
    const float* __restrict__ feat_l2c, const float* __restrict__ feat_c2l,
    const float* __restrict__ W_l2c, const float* __restrict__ b_l2c,
    const float* __restrict__ W_c2l, const float* __restrict__ b_c2l,
    unsigned short* __restrict__ h_l2c, unsigned short* __restrict__ h_c2l)
{
    int gid = blockIdx.x * 256 + threadIdx.x;
    if (gid >= EDGES * 8) return;
    int e = gid >> 3, fo = (gid & 7) << 3;
    float2 fl = *(const float2*)(feat_l2c + e * 2);
    float2 fc = *(const float2*)(feat_c2l + e * 2);

    u16x8 outl, outc;
#pragma unroll
    for (int j = 0; j < 8; ++j) {
        float wl0 = W_l2c[fo + j], wl1 = W_l2c[64 + fo + j];
        float wc0 = W_c2l[fo + j], wc1 = W_c2l[64 + fo + j];
        float vl = fl.x * wl0 + fl.y * wl1 + b_l2c[fo + j];
        float vc = fc.x * wc0 + fc.y * wc1 + b_c2l[fo + j];
        outl[j] = f2bf(vl);
        outc[j] = f2bf(vc);
    }
    *(u16x8*)(h_l2c + e * 64 + fo) = outl;
    *(u16x8*)(h_c2l + e * 64 + fo) = outc;
}

// -------- literal update (R5 structure; bf16 agg): x0=(agg-h)/8 -> MLP3 -> merge --------
__global__ __launch_bounds__(512, 4) void lit_update(
    const unsigned short* __restrict__ h_c2l,
    unsigned short* __restrict__ h_l2c,
    const unsigned short* __restrict__ agg,
    const int* __restrict__ lit_idx,
    const unsigned short* __restrict__ wT,
    const float* __restrict__ msgl_b,
    const float* __restrict__ merge_b0,
    const float* __restrict__ merge_br)
{
    __shared__ __align__(16) char lds[LIT_WBYTES + 384 * 4];   // 58880 B -> 2 blocks/CU
    int tid = threadIdx.x;
#pragma unroll
    for (int c = 0; c < 7; ++c) {
        int idx = c * 512 + tid;
        *(u16x8*)(lds + idx * 16) = *(const u16x8*)(wT + idx * 8);
    }
    float* ldsBias = (float*)(lds + LIT_WBYTES);
    if (tid < 384) {
        float v;
        if (tid < 192)      v = msgl_b[tid];
        else if (tid < 256) v = merge_b0[tid - 192];
        else                v = merge_br[tid - 256];
        ldsBias[tid] = v;
    }
    __syncthreads();

    int wv = tid >> 6, lane = tid & 63;
    int eL = lane & 31, hi = lane >> 5;
    int bpidx = (lane ^ 32) << 2;
    int base = blockIdx.x * EPB2 + wv * 32;
    if (base >= EDGES) return;
    int e = base + eL;
    int lit = lit_idx[e];

    // old h_l2c fragments (merge kb 4-7) -- load early, hide under msgl layers
    s16x8 hfrag[4];
#pragma unroll
    for (int k = 0; k < 4; ++k)
        hfrag[k] = *(const s16x8*)(h_l2c + e * 64 + 16 * k + 8 * hi);

    // input x0 fragments (agg is bf16 now)
    s16x8 binp[4];
#pragma unroll
    for (int k = 0; k < 4; ++k) {
        int f0 = 16 * k + 8 * hi;
        u16x8 ag = *(const u16x8*)(agg + lit * 64 + f0);
        u16x8 hv = *(const u16x8*)(h_c2l + e * 64 + f0);
        s16x8 b;
#pragma unroll
        for (int j = 0; j < 8; ++j)
            b[j] = (short)f2bf((bf2f(ag[j]) - bf2f(hv[j])) * 0.125f);
        binp[k] = b;
    }

    f32x16 acc[2];
    s16x8 bf[4];
    layer32(lds,            ldsBias,       binp, acc, eL, hi);
    relayout32<true >(acc, bf, bpidx, hi);
    layer32(lds + 8192,     ldsBias + 64,  bf, acc, eL, hi);
    relayout32<true >(acc, bf, bpidx, hi);
    layer32(lds + 2 * 8192, ldsBias + 128, bf, acc, eL, hi);
    relayout32<false>(acc, bf, bpidx, hi);        // m fragments

    // merge layer 0: K=128 = [m | h_old], units 3 (m) and 4 (h)
#pragma unroll
    for (int t = 0; t < 2; ++t)
#pragma unroll
        for (int g = 0; g < 4; ++g) {
            f32x4 bv = *(const f32x4*)(ldsBias + 192 + 32 * t + 8 * g + 4 * hi);
#pragma unroll
            for (int r = 0; r < 4; ++r) acc[t][4 * g + r] = bv[r];
        }
#pragma unroll
    for (int kb = 0; kb < 8; ++kb) {
        const char* ub = lds + (3 + (kb >> 2)) * 8192;
        s16x8 bop = (kb < 4) ? bf[kb] : hfrag[kb - 4];
#pragma unroll
        for (int t = 0; t < 2; ++t) {
            int row = 32 * t + eL;
            s16x8 a = *(const s16x8*)(ub + row * 128 +
                                      ((32 * (kb & 3) + 16 * hi) ^ ((row & 7) << 4)));
            acc[t] = mfma32(a, bop, acc[t]);
        }
    }
    relayout32<true>(acc, bf, bpidx, hi);
    layer32(lds + 5 * 8192, ldsBias + 256, bf, acc, eL, hi);
    relayout32<true>(acc, bf, bpidx, hi);
    layer32(lds + 6 * 8192, ldsBias + 320, bf, acc, eL, hi);

    store32(acc, h_l2c + e * 64, hi);
}

// -------- clause update; FINAL round fuses per-graph readout reduction --------
template<int FINAL>
__global__ __launch_bounds__(512, 4) void clause_update(
    const unsigned short* __restrict__ h_l2c,
    unsigned short* __restrict__ h_c2l,
    const unsigned short* __restrict__ msgcT,
    const float* __restrict__ msgc_b,
    float* __restrict__ ro_acc)
{
    __shared__ __align__(16) char lds[CLS_WBYTES + 192 * 4];   // 25344 B
    __shared__ float gsum[128];                                 // 2 graphs x 64 feats
    int tid = threadIdx.x;
#pragma unroll
    for (int c = 0; c < 3; ++c) {
        int idx = c * 512 + tid;
        *(u16x8*)(lds + idx * 16) = *(const u16x8*)(msgcT + idx * 8);
    }
    float* ldsBias = (float*)(lds + CLS_WBYTES);
    if (tid < 192) ldsBias[tid] = msgc_b[tid];
    if (FINAL && tid < 128) gsum[tid] = 0.f;
    __syncthreads();

    int wv = tid >> 6, lane = tid & 63;
    int eL = lane & 31, hi = lane >> 5;
    int bpidx = (lane ^ 32) << 2;
    int base = blockIdx.x * EPB2 + wv * 32;
    bool active = base < EDGES;
    int block_base = blockIdx.x * EPB2;
    int g_lo = block_base / EPG;

    if (active) {
        int e = base + eL;
        int c3 = (e / 3) * 3;
        int d = e - c3;
        int e1 = c3 + (d == 0 ? 1 : 0);
        int e2 = c3 + (d == 2 ? 1 : 2);

        s16x8 binp[4];
#pragma unroll
        for (int k = 0; k < 4; ++k) {
            int f0 = 16 * k + 8 * hi;
            u16x8 h1 = *(const u16x8*)(h_l2c + e1 * 64 + f0);
            u16x8 h2 = *(const u16x8*)(h_l2c + e2 * 64 + f0);
            s16x8 b;
#pragma unroll
            for (int j = 0; j < 8; ++j)
                b[j] = (short)f2bf((bf2f(h1[j]) + bf2f(h2[j])) * 0.125f);
            binp[k] = b;
        }

        f32x16 acc[2];
        s16x8 bf[4];
        layer32(lds,            ldsBias,       binp, acc, eL, hi);
        relayout32<true>(acc, bf, bpidx, hi);
        layer32(lds + 8192,     ldsBias + 64,  bf, acc, eL, hi);
        relayout32<true>(acc, bf, bpidx, hi);
        layer32(lds + 2 * 8192, ldsBias + 128, bf, acc, eL, hi);

        if (!FINAL) {
            store32(acc, h_c2l + e * 64, hi);
        } else {
            bool uniform = (base / EPG) == ((base + 31) / EPG);
            if (uniform) {
                // butterfly sum over the 32 edge-columns (stays within 32-lane half)
#pragma unroll
                for (int m = 1; m < 32; m <<= 1)
#pragma unroll
                    for (int t = 0; t < 2; ++t)
#pragma unroll
                        for (int i = 0; i < 16; ++i)
                            acc[t][i] += __shfl_xor(acc[t][i], m, 64);
                if (eL == 0) {
                    int gslot = (base / EPG) - g_lo;   // 0 or 1
#pragma unroll
                    for (int t = 0; t < 2; ++t)
#pragma unroll
                        for (int g = 0; g < 4; ++g)
#pragma unroll
                            for (int r = 0; r < 4; ++r)
                                atomicAdd(&gsum[gslot * 64 + 32 * t + 8 * g + 4 * hi + r],
                                          acc[t][4 * g + r]);
                }
            } else {
                // rare graph-straddling wave: per-lane direct global atomics
                int g = e / EPG;
#pragma unroll
                for (int t = 0; t < 2; ++t)
#pragma unroll
                    for (int gg = 0; gg < 4; ++gg)
#pragma unroll
                        for (int r = 0; r < 4; ++r)
                            atomicAdd(&ro_acc[g * 64 + 32 * t + 8 * gg + 4 * hi + r],
                                      acc[t][4 * gg + r]);
            }
        }
    }

    if (FINAL) {
        __syncthreads();
        if (tid < 128) {
            int slot = tid >> 6;
            int last = block_base + EPB2 - 1;
            if (last >= EDGES) last = EDGES - 1;
            int g_hi = last / EPG;
            int g = g_lo + slot;
            if (slot == 0 || g_hi > g_lo)
                atomicAdd(&ro_acc[g * 64 + (tid & 63)], gsum[tid]);
        }
    }
}

// -------- readout stage 2: tiny MLP + sigmoid --------
__global__ __launch_bounds__(256) void readout_mlp(
    const float* __restrict__ ro_acc, const float* __restrict__ ro_W,
    const float* __restrict__ ro_b, const float* __restrict__ ro_W2,
    const float* __restrict__ ro_b2, float* __restrict__ out)
{
    __shared__ float xb[NGRAPH][HDIM];
    __shared__ float yb[NGRAPH][HDIM];
    int g = threadIdx.x >> 6;
    int j = threadIdx.x & 63;
    xb[g][j] = ro_acc[g * HDIM + j] * (1.0f / 12500.0f);
    __syncthreads();
    float a = ro_b[j];
#pragma unroll 8
    for (int k = 0; k < HDIM; ++k) a += xb[g][k] * ro_W[k * HDIM + j];
    a = fmaxf(a, 0.0f);
    yb[g][j] = a;
    __syncthreads();
    float a2 = ro_b[HDIM + j];
#pragma unroll 8
    for (int k = 0; k < HDIM; ++k) a2 += yb[g][k] * ro_W[4096 + k * HDIM + j];
    a2 = fmaxf(a2, 0.0f);
    float p = a2 * ro_W2[j];
#pragma unroll
    for (int off = 32; off > 0; off >>= 1) p += __shfl_down(p, off, 64);
    if (j == 0) out[g] = 1.0f / (1.0f + expf(-(p + ro_b2[0])));
}

extern "C" void kernel_launch(void* const* d_in, const int* in_sizes, int n_in,
                              void* d_out, int out_size, void* d_ws, size_t ws_size,
                              hipStream_t stream)
{
    const float* feat_l2c = (const float*)d_in[0];
    const float* feat_c2l = (const float*)d_in[1];
    const int*   lit_idx  = (const int*)d_in[2];
    // d_in[3] (cls_idx) unused: edges are clause-major by construction
    const float* W_l2c    = (const float*)d_in[4];
    const float* b_l2c    = (const float*)d_in[5];
    const float* W_c2l    = (const float*)d_in[6];
    const float* b_c2l    = (const float*)d_in[7];
    const float* msgl_W   = (const float*)d_in[8];
    const float* msgl_b   = (const float*)d_in[9];
    const float* merge_W0 = (const float*)d_in[10];
    const float* merge_b0 = (const float*)d_in[11];
    const float* merge_Wr = (const float*)d_in[12];
    const float* merge_br = (const float*)d_in[13];
    const float* msgc_W   = (const float*)d_in[14];
    const float* msgc_b   = (const float*)d_in[15];
    const float* ro_W     = (const float*)d_in[16];
    const float* ro_b     = (const float*)d_in[17];
    const float* ro_W2    = (const float*)d_in[18];
    const float* ro_b2    = (const float*)d_in[19];

    char* ws = (char*)d_ws;
    unsigned short* h_l2c  = (unsigned short*)(ws + OFF_HL2C);
    unsigned short* h_c2l  = (unsigned short*)(ws + OFF_HC2L);
    unsigned short* agg    = (unsigned short*)(ws + OFF_AGG);
    unsigned short* wT     = (unsigned short*)(ws + OFF_WT);
    float*          ro_acc = (float*)(ws + OFF_ROACC);
    int*            cnt    = (int*)(ws + OFF_CNT);
    int*            csroff = (int*)(ws + OFF_CSROFF);
    int*            cursor = (int*)(ws + OFF_CURSOR);
    int*            eidx   = (int*)(ws + OFF_EIDX);
    int*            bsum   = (int*)(ws + OFF_BSUM);
    int*            bbase  = (int*)(ws + OFF_BBASE);

    hipMemsetAsync(cnt, 0, NLIT * sizeof(int), stream);
    hipMemsetAsync(ro_acc, 0, NGRAPH * 64 * sizeof(float), stream);

    prep_weights<<<(WT_TOTAL + 255) / 256, 256, 0, stream>>>(msgl_W, merge_W0, merge_Wr, msgc_W, wT);

    // CSR of lit_idx (per-launch rebuild; 3-stage parallel scan)
    csr_hist<<<(EDGES + 255) / 256, 256, 0, stream>>>(lit_idx, cnt);
    scan1<<<SCAN_BLOCKS, 256, 0, stream>>>(cnt, bsum);
    scan2<<<1, 256, 0, stream>>>(bsum, bbase);
    scan3<<<SCAN_BLOCKS, 256, 0, stream>>>(cnt, bbase, csroff, cursor);
    csr_scatter<<<(EDGES + 255) / 256, 256, 0, stream>>>(lit_idx, cursor, eidx);

    init_kernel<<<EDGES * 8 / 256, 256, 0, stream>>>(feat_l2c, feat_c2l, W_l2c, b_l2c,
                                                     W_c2l, b_c2l, h_l2c, h_c2l);
    for (int r = 0; r < 3; ++r) {
        aggregate<<<(NLIT + 31) / 32, 256, 0, stream>>>(h_c2l, csroff, eidx, agg);
        lit_update<<<GRID_EDGE, 512, 0, stream>>>(h_c2l, h_l2c, agg, lit_idx, wT,
                                                  msgl_b, merge_b0, merge_br);
        if (r < 2)
            clause_update<0><<<GRID_EDGE, 512, 0, stream>>>(h_l2c, h_c2l,
                                                            wT + WT_CLS_ELEM, msgc_b, ro_acc);
        else
            clause_update<1><<<GRID_EDGE, 512, 0, stream>>>(h_l2c, h_c2l,
                                                            wT + WT_CLS_ELEM, msgc_b, ro_acc);
    }
    readout_mlp<<<1, 256, 0, stream>>>(ro_acc, ro_W, ro_b, ro_W2, ro_b2, (float*)d_out);
}